// Round 6
// baseline (143.941 us; speedup 1.0000x reference)
//
#include <hip/hip_runtime.h>
#include <hip/hip_bf16.h>

#define N_TOK 16384
#define B_DIM 8
#define C_DIM 256
#define M_ROWS (N_TOK * B_DIM)   // 131072
#define BM 32
#define TPB 8
#define GRID 512                  // 2 blocks/CU, persistent

typedef __attribute__((ext_vector_type(8))) short short8;
typedef __attribute__((ext_vector_type(4))) float f32x4;

__device__ __forceinline__ unsigned short f2bf(float f) {
    union { float f; unsigned u; } v; v.f = f;
    unsigned r = v.u + 0x7fffu + ((v.u >> 16) & 1u);  // RNE
    return (unsigned short)(r >> 16);
}

__device__ __forceinline__ unsigned cvt_pk(float a, float b) {
    unsigned r;
    asm("v_cvt_pk_bf16_f32 %0, %1, %2" : "=v"(r) : "v"(a), "v"(b));
    return r;
}

__device__ __forceinline__ void gload_lds16(const void* g, void* l) {
    __builtin_amdgcn_global_load_lds(
        (const __attribute__((address_space(1))) void*)g,
        (__attribute__((address_space(3))) void*)l, 16, 0, 0);
}

// Kernel A: m -> d_out tail; W fp32 -> bf16 in MFMA-fragment order.
// Wf[((ctile*8 + k8)*64 + lane)*8 + r] = bf16(W[ctile*16 + (lane&15)][k8*32 + (lane>>4)*8 + r])
__global__ __launch_bounds__(256)
void prep_kernel(const int* __restrict__ mask, const int* __restrict__ fg,
                 const float* __restrict__ W, unsigned short* __restrict__ Wf,
                 float* __restrict__ m_out) {
    int i = blockIdx.x * 256 + threadIdx.x;
    if (i < C_DIM * C_DIM) {
        int d = i >> 8;            // W row = output col
        int c = i & 255;           // k
        int ctile = d >> 4;
        int k8    = c >> 5;
        int lane  = ((c >> 3) & 3) * 16 + (d & 15);
        int r     = c & 7;
        Wf[((ctile * 8 + k8) * 64 + lane) * 8 + r] = f2bf(W[i]);
    }
    if (i < M_ROWS) {
        int b = i & (B_DIM - 1);
        int n = i >> 3;
        m_out[i] = (fg[i] != 0) ? (1.0f - (float)mask[b * N_TOK + n]) : 0.0f;
    }
}

// Kernel B: persistent, counted-vmcnt pipelined. 8 waves x 32 cols; W in regs;
// compute phase has ZERO VMEM; stores/next-stage stay in flight across barriers.
__global__ __launch_bounds__(512, 4)
void mlp_kernel(const float* __restrict__ x, const unsigned short* __restrict__ Wf,
                const float* __restrict__ bias, const float* __restrict__ m,
                float* __restrict__ out) {
    __shared__ float lds[2][BM * C_DIM];   // 2 x 32 KB fp32, XOR-swizzled content

    const int t    = threadIdx.x;
    const int lane = t & 63;
    const int wid  = t >> 6;            // 0..7 : col slice [wid*32, wid*32+32)
    const int lr   = lane & 15;
    const int kb   = (lane >> 4) * 8;
    const int rsub = (lane >> 4) * 4;

    const int tile0 = blockIdx.x * TPB;

    // ---- W operand in registers: 2 ctiles x 8 k-steps, coalesced loads ----
    short8 wreg[2][8];
    #pragma unroll
    for (int c2 = 0; c2 < 2; ++c2)
        #pragma unroll
        for (int k8 = 0; k8 < 8; ++k8)
            wreg[c2][k8] = ((const short8*)Wf)[((wid * 2 + c2) * 8 + k8) * 64 + lane];
    #pragma unroll
    for (int c2 = 0; c2 < 2; ++c2)
        #pragma unroll
        for (int k8 = 0; k8 < 8; ++k8)
            asm volatile("" : "+v"(wreg[c2][k8]));   // pin: defeat remat/spill

    float bv[2];
    #pragma unroll
    for (int c2 = 0; c2 < 2; ++c2) bv[c2] = bias[wid * 32 + c2 * 16 + lr];

    // ---- stage: wave wid DMAs rows [wid*4, wid*4+4); linear LDS dest,
    //      inverse-swizzled global source (rule 21) ----
    auto stage = [&](int buf, int tile) {
        const char* xb = (const char*)x + (size_t)tile * BM * 1024;
        #pragma unroll
        for (int r = 0; r < 4; ++r) {
            int row = wid * 4 + r;
            gload_lds16(xb + row * 1024 + ((lane * 16) ^ ((row & 7) << 4)),
                        (char*)&lds[buf][0] + row * 1024);
        }
    };

    float4 mA, mB, mA_n, mB_n;
    stage(0, tile0);                                   // 4 DMA
    mA = *(const float4*)(m + tile0 * BM + rsub);      // 2 m loads
    mB = *(const float4*)(m + tile0 * BM + 16 + rsub);

    for (int tt = 0; tt < TPB; ++tt) {
        const int tile = tile0 + tt;
        const int cur  = tt & 1;

        // wait: stage(t)+m(t) done; stores(t-1) [<=16] may remain in flight
        if (tt == 0) asm volatile("s_waitcnt vmcnt(0)" ::: "memory");
        else         asm volatile("s_waitcnt vmcnt(16)" ::: "memory");
        __builtin_amdgcn_s_barrier();

        if (tt + 1 < TPB) {                 // prefetch BEFORE this tile's stores
            stage(cur ^ 1, tile + 1);
            mA_n = *(const float4*)(m + (tile + 1) * BM + rsub);
            mB_n = *(const float4*)(m + (tile + 1) * BM + 16 + rsub);
        }

        // ---- compute: pure LDS + MFMA ----
        const char* Lc = (const char*)&lds[cur][0];
        f32x4 acc[2][2];
        #pragma unroll
        for (int i = 0; i < 2; ++i)
            #pragma unroll
            for (int j = 0; j < 2; ++j) acc[i][j] = (f32x4){0.f, 0.f, 0.f, 0.f};

        #pragma unroll
        for (int k8 = 0; k8 < 8; ++k8) {
            short8 af[2];
            #pragma unroll
            for (int rt = 0; rt < 2; ++rt) {
                int row  = rt * 16 + lr;
                int sz   = (row & 7) << 4;
                int base = row * 1024 + (k8 * 32 + kb) * 4;
                float4 f0 = *(const float4*)(Lc + (base ^ sz));
                float4 f1 = *(const float4*)(Lc + ((base + 16) ^ sz));
                int4 pk;
                pk.x = (int)cvt_pk(f0.x, f0.y);
                pk.y = (int)cvt_pk(f0.z, f0.w);
                pk.z = (int)cvt_pk(f1.x, f1.y);
                pk.w = (int)cvt_pk(f1.z, f1.w);
                af[rt] = *(const short8*)&pk;
            }
            #pragma unroll
            for (int rt = 0; rt < 2; ++rt)
                #pragma unroll
                for (int c2 = 0; c2 < 2; ++c2)
                    acc[rt][c2] = __builtin_amdgcn_mfma_f32_16x16x32_bf16(
                        af[rt], wreg[c2][k8], acc[rt][c2], 0, 0, 0);
        }

        // ---- epilogue: relu(acc+b), select vs exact fp32 x from LDS ----
        #pragma unroll
        for (int rt = 0; rt < 2; ++rt) {
            float4 mr = rt ? mB : mA;
            #pragma unroll
            for (int r = 0; r < 4; ++r) {
                int lrow = rt * 16 + rsub + r;
                float mv = (r == 0) ? mr.x : (r == 1) ? mr.y : (r == 2) ? mr.z : mr.w;
                size_t grow = (size_t)tile * BM + lrow;
                #pragma unroll
                for (int c2 = 0; c2 < 2; ++c2) {
                    int col = wid * 32 + c2 * 16 + lr;
                    float y  = fmaxf(acc[rt][c2][r] + bv[c2], 0.0f);
                    float xv = *(const float*)(Lc + ((lrow * 1024 + col * 4) ^ ((lrow & 7) << 4)));
                    out[grow * C_DIM + col] = (mv != 0.0f) ? y : xv;
                }
            }
        }

        mA = mA_n; mB = mB_n;
        __builtin_amdgcn_s_barrier();   // all reads of buf done before its restage
    }
}

extern "C" void kernel_launch(void* const* d_in, const int* in_sizes, int n_in,
                              void* d_out, int out_size, void* d_ws, size_t ws_size,
                              hipStream_t stream) {
    const float* x    = (const float*)d_in[0];
    const int*   mask = (const int*)d_in[1];
    const int*   fg   = (const int*)d_in[2];
    const float* W    = (const float*)d_in[3];
    const float* b    = (const float*)d_in[4];

    float* out   = (float*)d_out;
    float* m_out = out + (size_t)M_ROWS * C_DIM;      // output 1: m (N,B)
    unsigned short* Wf = (unsigned short*)d_ws;       // 128 KB fragment-order W

    prep_kernel<<<M_ROWS / 256, 256, 0, stream>>>(mask, fg, W, Wf, m_out);
    mlp_kernel<<<GRID, 512, 0, stream>>>(x, Wf, b, m_out, out);
}

// Round 7
// 103.441 us; speedup vs baseline: 1.3915x; 1.3915x over previous
//
#include <hip/hip_runtime.h>
#include <hip/hip_bf16.h>

#define N_TOK 16384
#define B_DIM 8
#define C_DIM 256
#define M_ROWS (N_TOK * B_DIM)   // 131072
#define BM 32

typedef __attribute__((ext_vector_type(8))) short short8;
typedef __attribute__((ext_vector_type(4))) float f32x4;

__device__ __forceinline__ unsigned short f2bf(float f) {
    union { float f; unsigned u; } v; v.f = f;
    unsigned r = v.u + 0x7fffu + ((v.u >> 16) & 1u);  // RNE
    return (unsigned short)(r >> 16);
}

// packed RNE f32x2 -> bf16x2 (low = a, high = b)
__device__ __forceinline__ unsigned cvt_pk(float a, float b) {
    unsigned r;
    asm("v_cvt_pk_bf16_f32 %0, %1, %2" : "=v"(r) : "v"(a), "v"(b));
    return r;
}

// Kernel A: m -> d_out tail; W fp32 -> bf16 in MFMA-fragment order.
// Wf[((ctile*8 + k8)*64 + lane)*8 + r] = bf16(W[ctile*16 + (lane&15)][k8*32 + (lane>>4)*8 + r])
__global__ __launch_bounds__(256)
void prep_kernel(const int* __restrict__ mask, const int* __restrict__ fg,
                 const float* __restrict__ W, unsigned short* __restrict__ Wf,
                 float* __restrict__ m_out) {
    int i = blockIdx.x * 256 + threadIdx.x;
    if (i < C_DIM * C_DIM) {
        int d = i >> 8;            // W row = output col
        int c = i & 255;           // k
        int ctile = d >> 4;
        int k8    = c >> 5;
        int lane  = ((c >> 3) & 3) * 16 + (d & 15);
        int r     = c & 7;
        Wf[((ctile * 8 + k8) * 64 + lane) * 8 + r] = f2bf(W[i]);
    }
    if (i < M_ROWS) {
        int b = i & (B_DIM - 1);
        int n = i >> 3;
        m_out[i] = (fg[i] != 0) ? (1.0f - (float)mask[b * N_TOK + n]) : 0.0f;
    }
}

// Kernel B: LDS-free, barrier-free streaming GEMM. 4096 blocks x 4 waves;
// each wave: 32 rows x 64 cols. A-fragments coalesced straight from global
// (16 full 128B lines per load instr; 4x wave sharing absorbed by L2),
// W-fragments from fragment-ordered L2-resident buffer. 1-deep prefetch on
// both. fp32->bf16 via cvt_pk in-flight. Epilogue reads exact fp32 x (L2-hot).
__global__ __launch_bounds__(256, 4)
void mlp_kernel(const float* __restrict__ x, const unsigned short* __restrict__ Wf,
                const float* __restrict__ bias, const float* __restrict__ m,
                float* __restrict__ out) {
    const int t    = threadIdx.x;
    const int lane = t & 63;
    const int wid  = t >> 6;           // 0..3 : col slice [wid*64, wid*64+64)
    const int lr   = lane & 15;
    const int kq   = lane >> 4;        // 0..3
    const int rsub = kq * 4;           // C/D: row = (lane>>4)*4 + reg
    const int row0 = blockIdx.x * BM;
    const int col0 = wid * 64;

    // Per-lane A source base: row (rt*16 + lr), k-bytes (k8*128 + kq*32)
    const char* xbA = (const char*)(x + (size_t)row0 * C_DIM) + lr * 1024 + kq * 32;
    const short8* wf = (const short8*)Wf + lane;

    f32x4 acc[2][4];
    #pragma unroll
    for (int i = 0; i < 2; ++i)
        #pragma unroll
        for (int j = 0; j < 4; ++j) acc[i][j] = (f32x4){0.f, 0.f, 0.f, 0.f};

    float4 a_cur[2][2], a_nxt[2][2];
    short8 w_cur[4], w_nxt[4];

    // ---- prefetch k8 = 0 ----
    #pragma unroll
    for (int rt = 0; rt < 2; ++rt) {
        a_cur[rt][0] = *(const float4*)(xbA + rt * 16384);
        a_cur[rt][1] = *(const float4*)(xbA + rt * 16384 + 16);
    }
    #pragma unroll
    for (int ct = 0; ct < 4; ++ct)
        w_cur[ct] = wf[((wid * 4 + ct) * 8) * 64];

    #pragma unroll
    for (int k8 = 0; k8 < 8; ++k8) {
        if (k8 < 7) {
            #pragma unroll
            for (int rt = 0; rt < 2; ++rt) {
                a_nxt[rt][0] = *(const float4*)(xbA + rt * 16384 + (k8 + 1) * 128);
                a_nxt[rt][1] = *(const float4*)(xbA + rt * 16384 + (k8 + 1) * 128 + 16);
            }
            #pragma unroll
            for (int ct = 0; ct < 4; ++ct)
                w_nxt[ct] = wf[((wid * 4 + ct) * 8 + k8 + 1) * 64];
        }
        short8 af[2];
        #pragma unroll
        for (int rt = 0; rt < 2; ++rt) {
            int4 pk;
            pk.x = (int)cvt_pk(a_cur[rt][0].x, a_cur[rt][0].y);
            pk.y = (int)cvt_pk(a_cur[rt][0].z, a_cur[rt][0].w);
            pk.z = (int)cvt_pk(a_cur[rt][1].x, a_cur[rt][1].y);
            pk.w = (int)cvt_pk(a_cur[rt][1].z, a_cur[rt][1].w);
            af[rt] = *(const short8*)&pk;
        }
        #pragma unroll
        for (int rt = 0; rt < 2; ++rt)
            #pragma unroll
            for (int ct = 0; ct < 4; ++ct)
                acc[rt][ct] = __builtin_amdgcn_mfma_f32_16x16x32_bf16(
                    af[rt], w_cur[ct], acc[rt][ct], 0, 0, 0);
        #pragma unroll
        for (int rt = 0; rt < 2; ++rt) {
            a_cur[rt][0] = a_nxt[rt][0];
            a_cur[rt][1] = a_nxt[rt][1];
        }
        #pragma unroll
        for (int ct = 0; ct < 4; ++ct) w_cur[ct] = w_nxt[ct];
    }

    // ---- Epilogue: relu(acc+b), select vs exact fp32 x (L2-hot), store ----
    float bv[4];
    #pragma unroll
    for (int ct = 0; ct < 4; ++ct) bv[ct] = bias[col0 + ct * 16 + lr];

    #pragma unroll
    for (int rt = 0; rt < 2; ++rt) {
        float4 mr = *(const float4*)(m + row0 + rt * 16 + rsub);
        #pragma unroll
        for (int r = 0; r < 4; ++r) {
            int lrow = rt * 16 + rsub + r;
            float mv = (r == 0) ? mr.x : (r == 1) ? mr.y : (r == 2) ? mr.z : mr.w;
            size_t grow = (size_t)row0 + lrow;
            #pragma unroll
            for (int ct = 0; ct < 4; ++ct) {
                int col = col0 + ct * 16 + lr;
                float y  = fmaxf(acc[rt][ct][r] + bv[ct], 0.0f);
                float xv = x[grow * C_DIM + col];
                out[grow * C_DIM + col] = (mv != 0.0f) ? y : xv;
            }
        }
    }
}

extern "C" void kernel_launch(void* const* d_in, const int* in_sizes, int n_in,
                              void* d_out, int out_size, void* d_ws, size_t ws_size,
                              hipStream_t stream) {
    const float* x    = (const float*)d_in[0];
    const int*   mask = (const int*)d_in[1];
    const int*   fg   = (const int*)d_in[2];
    const float* W    = (const float*)d_in[3];
    const float* b    = (const float*)d_in[4];

    float* out   = (float*)d_out;
    float* m_out = out + (size_t)M_ROWS * C_DIM;      // output 1: m (N,B)
    unsigned short* Wf = (unsigned short*)d_ws;       // 128 KB fragment-order W

    prep_kernel<<<M_ROWS / 256, 256, 0, stream>>>(mask, fg, W, Wf, m_out);
    mlp_kernel<<<M_ROWS / BM, 256, 0, stream>>>(x, Wf, b, m_out, out);
}

// Round 8
// 61.352 us; speedup vs baseline: 2.3461x; 1.6860x over previous
//
#include <hip/hip_runtime.h>
#include <hip/hip_bf16.h>

#define N_TOK 16384
#define B_DIM 8
#define C_DIM 256
#define M_ROWS (N_TOK * B_DIM)   // 131072
#define BM 32

typedef __attribute__((ext_vector_type(8))) short short8;
typedef __attribute__((ext_vector_type(4))) float f32x4;

__device__ __forceinline__ unsigned short f2bf(float f) {
    union { float f; unsigned u; } v; v.f = f;
    unsigned r = v.u + 0x7fffu + ((v.u >> 16) & 1u);  // RNE
    return (unsigned short)(r >> 16);
}

__device__ __forceinline__ float bf2f(unsigned short h) {
    union { unsigned u; float f; } v; v.u = ((unsigned)h) << 16;
    return v.f;
}

// packed RNE f32x2 -> bf16x2 (low = a, high = b)
__device__ __forceinline__ unsigned cvt_pk(float a, float b) {
    unsigned r;
    asm("v_cvt_pk_bf16_f32 %0, %1, %2" : "=v"(r) : "v"(a), "v"(b));
    return r;
}

// Kernel A: m -> d_out tail; W fp32 -> bf16 in MFMA-fragment order.
// Wf[((ctile*8 + k8)*64 + lane)*8 + r] = bf16(W[ctile*16 + (lane&15)][k8*32 + (lane>>4)*8 + r])
__global__ __launch_bounds__(256)
void prep_kernel(const int* __restrict__ mask, const int* __restrict__ fg,
                 const float* __restrict__ W, unsigned short* __restrict__ Wf,
                 float* __restrict__ m_out) {
    int i = blockIdx.x * 256 + threadIdx.x;
    if (i < C_DIM * C_DIM) {
        int d = i >> 8;            // W row = output col
        int c = i & 255;           // k
        int ctile = d >> 4;
        int k8    = c >> 5;
        int lane  = ((c >> 3) & 3) * 16 + (d & 15);
        int r     = c & 7;
        Wf[((ctile * 8 + k8) * 64 + lane) * 8 + r] = f2bf(W[i]);
    }
    if (i < M_ROWS) {
        int b = i & (B_DIM - 1);
        int n = i >> 3;
        m_out[i] = (fg[i] != 0) ? (1.0f - (float)mask[b * N_TOK + n]) : 0.0f;
    }
}

// Kernel B: 32-row tile per block (4096 blocks); bf16 x in 16 KB LDS
// (XOR-swizzled); W fragments coalesced from L2 with 1-deep prefetch;
// fused relu+select epilogue reading x back from LDS.
__global__ __launch_bounds__(256, 4)
void mlp_kernel(const float* __restrict__ x, const unsigned short* __restrict__ Wf,
                const float* __restrict__ bias, const float* __restrict__ m,
                float* __restrict__ out) {
    __shared__ unsigned short lds_x[BM * C_DIM];  // 16 KB bf16

    const int t    = threadIdx.x;
    const int row0 = blockIdx.x * BM;

    // ---- Stage x tile (32 x 256 fp32 -> bf16 LDS), coalesced 32B/lane ----
    #pragma unroll
    for (int j = 0; j < 4; ++j) {
        int ci  = j * 256 + t;
        int row = ci >> 5;            // 0..31
        int cc  = (ci & 31) * 8;      // 0..248
        const float4* p = (const float4*)(x + (size_t)(row0 + row) * C_DIM + cc);
        float4 a0 = p[0];
        float4 a1 = p[1];
        int4 pk;
        pk.x = (int)cvt_pk(a0.x, a0.y);
        pk.y = (int)cvt_pk(a0.z, a0.w);
        pk.z = (int)cvt_pk(a1.x, a1.y);
        pk.w = (int)cvt_pk(a1.z, a1.w);
        int byte = (row * 512 + cc * 2) ^ ((row & 7) << 4);
        *(int4*)((char*)lds_x + byte) = pk;
    }
    __syncthreads();

    // ---- MFMA: 4 waves x 64 cols, 2(row) x 4(col) 16x16 tiles each ----
    const int lane = t & 63;
    const int wid  = t >> 6;
    const int col0 = wid * 64;
    const int lr   = lane & 15;
    const int kb   = (lane >> 4) * 8;
    const int rsub = (lane >> 4) * 4;   // C/D: row = (lane>>4)*4 + reg

    f32x4 acc[2][4];
    #pragma unroll
    for (int i = 0; i < 2; ++i)
        #pragma unroll
        for (int j = 0; j < 4; ++j) acc[i][j] = (f32x4){0.f, 0.f, 0.f, 0.f};

    // Wave's fragment base: ctile = wid*4 + ct
    const short8* wfb = (const short8*)Wf + (size_t)wid * 4 * 8 * 64 + lane;

    short8 wcur[4], wnxt[4];
    #pragma unroll
    for (int ct = 0; ct < 4; ++ct)
        wcur[ct] = wfb[(ct * 8) * 64];            // k8 = 0, 1 KB coalesced/wave

    #pragma unroll
    for (int k8 = 0; k8 < 8; ++k8) {
        if (k8 < 7) {                              // 1-deep W prefetch from L2
            #pragma unroll
            for (int ct = 0; ct < 4; ++ct)
                wnxt[ct] = wfb[(ct * 8 + k8 + 1) * 64];
        }
        short8 af[2];
        #pragma unroll
        for (int rt = 0; rt < 2; ++rt) {
            int row  = rt * 16 + lr;
            int byte = (row * 512 + (k8 * 32 + kb) * 2) ^ ((row & 7) << 4);
            af[rt] = *(const short8*)((const char*)lds_x + byte);
        }
        #pragma unroll
        for (int rt = 0; rt < 2; ++rt)
            #pragma unroll
            for (int ct = 0; ct < 4; ++ct)
                acc[rt][ct] = __builtin_amdgcn_mfma_f32_16x16x32_bf16(
                    af[rt], wcur[ct], acc[rt][ct], 0, 0, 0);
        #pragma unroll
        for (int ct = 0; ct < 4; ++ct) wcur[ct] = wnxt[ct];
    }

    // ---- Epilogue: relu(acc+b), select vs x (bf16 from LDS), store ----
    float bv[4];
    #pragma unroll
    for (int ct = 0; ct < 4; ++ct) bv[ct] = bias[col0 + ct * 16 + lr];

    #pragma unroll
    for (int rt = 0; rt < 2; ++rt) {
        float4 mreg = *(const float4*)(m + row0 + rt * 16 + rsub);
        #pragma unroll
        for (int r = 0; r < 4; ++r) {
            int lrow = rt * 16 + rsub + r;
            float mv = (r == 0) ? mreg.x : (r == 1) ? mreg.y
                     : (r == 2) ? mreg.z : mreg.w;
            size_t grow = (size_t)row0 + lrow;
            #pragma unroll
            for (int ct = 0; ct < 4; ++ct) {
                int col = col0 + ct * 16 + lr;
                float y = fmaxf(acc[rt][ct][r] + bv[ct], 0.0f);
                int bo = (lrow * 512 + col * 2) ^ ((lrow & 7) << 4);
                float xv = bf2f(*(const unsigned short*)((const char*)lds_x + bo));
                out[grow * C_DIM + col] = (mv != 0.0f) ? y : xv;
            }
        }
    }
}

extern "C" void kernel_launch(void* const* d_in, const int* in_sizes, int n_in,
                              void* d_out, int out_size, void* d_ws, size_t ws_size,
                              hipStream_t stream) {
    const float* x    = (const float*)d_in[0];
    const int*   mask = (const int*)d_in[1];
    const int*   fg   = (const int*)d_in[2];
    const float* W    = (const float*)d_in[3];
    const float* b    = (const float*)d_in[4];

    float* out   = (float*)d_out;
    float* m_out = out + (size_t)M_ROWS * C_DIM;      // output 1: m (N,B)
    unsigned short* Wf = (unsigned short*)d_ws;       // 128 KB fragment-order W

    prep_kernel<<<M_ROWS / 256, 256, 0, stream>>>(mask, fg, W, Wf, m_out);
    mlp_kernel<<<M_ROWS / BM, 256, 0, stream>>>(x, Wf, b, m_out, out);
}